// Round 15
// baseline (128.874 us; speedup 1.0000x reference)
//
#include <hip/hip_runtime.h>
#include <hip/hip_bf16.h>

#define LEAKY(v) ((v) > 0.0f ? (v) : 0.01f * (v))

constexpr int B_   = 1024;
constexpr int PAD  = 30;
constexpr int E    = 512;
constexpr int IMG  = 2048;
constexpr int C1   = 200;
constexpr int C2   = 300;
constexpr int C3   = 300;
constexpr int LIN2 = 400;

constexpr int NT1P = 16, KT1 = 48;
constexpr int NT2P = 20, KT2 = 21;
constexpr int NT3P = 24, KT3 = 30;
constexpr int NTMP = 28, KTM = 83;
constexpr int FK  = 2656;

constexpr int T1 = NT1P * KT1;       // 768
constexpr int T2 = NT2P * KT2;       // 420
constexpr int T3 = NT3P * KT3;       // 720
constexpr int TM = NTMP * KTM;       // 2324
constexpr int TTOT = T1 + T2 + T3 + TM;

typedef __attribute__((ext_vector_type(8))) short bf16x8;
typedef __attribute__((ext_vector_type(4))) float f32x4;

__device__ inline unsigned short f2bf(float f) {
    __hip_bfloat16 h = __float2bfloat16(f);
    return *reinterpret_cast<unsigned short*>(&h);
}
__device__ inline float bf2f(unsigned short u) {
    unsigned int b = ((unsigned int)u) << 16;
    return __uint_as_float(b);
}

// ================= fused weight converter (unchanged, verified) =================
__global__ __launch_bounds__(256) void convert_all(
    const float* __restrict__ W1, const float* __restrict__ W2,
    const float* __restrict__ W3, const float* __restrict__ Wm,
    unsigned short* __restrict__ W1t, unsigned short* __restrict__ W2t,
    unsigned short* __restrict__ W3t, unsigned short* __restrict__ Wmt)
{
    int idx = blockIdx.x * 256 + threadIdx.x;
    if (idx >= TTOT * 64) return;
    int lane = idx & 63, t = idx >> 6;
    unsigned short v[8];

    if (t < T1) {
        int kk = t % KT1, nt = t / KT1;
        int ch = nt * 16 + (lane & 15);
        int k0 = kk * 32 + (lane >> 4) * 8;
        #pragma unroll
        for (int j = 0; j < 8; ++j)
            v[j] = (ch < C1) ? f2bf(W1[(size_t)ch * (3*E) + k0 + j]) : (unsigned short)0;
        ushort4* dst = reinterpret_cast<ushort4*>(W1t) + (size_t)t * 128 + lane * 2;
        dst[0] = ushort4{v[0],v[1],v[2],v[3]};
        dst[1] = ushort4{v[4],v[5],v[6],v[7]};
    } else if (t < T1 + T2) {
        int tt = t - T1;
        int kk = tt % KT2, nt = tt / KT2;
        int ch = nt * 16 + (lane & 15);
        int rowoff = kk / 7;
        int cbase  = (kk % 7) * 32 + (lane >> 4) * 8;
        #pragma unroll
        for (int j = 0; j < 8; ++j) {
            int c = cbase + j;
            v[j] = (ch < C2 && c < C1) ? f2bf(W2[(size_t)ch * (3*C1) + rowoff * C1 + c])
                                       : (unsigned short)0;
        }
        ushort4* dst = reinterpret_cast<ushort4*>(W2t) + (size_t)tt * 128 + lane * 2;
        dst[0] = ushort4{v[0],v[1],v[2],v[3]};
        dst[1] = ushort4{v[4],v[5],v[6],v[7]};
    } else if (t < T1 + T2 + T3) {
        int tt = t - T1 - T2;
        int kk = tt % KT3, nt = tt / KT3;
        int ch = nt * 16 + (lane & 15);
        int rowoff = kk / 10;
        int cbase  = (kk % 10) * 32 + (lane >> 4) * 8;
        #pragma unroll
        for (int j = 0; j < 8; ++j) {
            int c = cbase + j;
            v[j] = (ch < C3 && c < C2) ? f2bf(W3[(size_t)ch * (3*C2) + rowoff * C2 + c])
                                       : (unsigned short)0;
        }
        ushort4* dst = reinterpret_cast<ushort4*>(W3t) + (size_t)tt * 128 + lane * 2;
        dst[0] = ushort4{v[0],v[1],v[2],v[3]};
        dst[1] = ushort4{v[4],v[5],v[6],v[7]};
    } else {
        int tt = t - T1 - T2 - T3;
        int kk = tt % KTM, nt = tt / KTM;
        int ch = nt * 16 + (lane & 15);
        int kbase = kk * 32 + (lane >> 4) * 8;
        #pragma unroll
        for (int j = 0; j < 8; ++j) {
            int k = kbase + j;
            v[j] = (ch < LIN2 && k < 2648) ? f2bf(Wm[(size_t)ch * 2648 + k])
                                           : (unsigned short)0;
        }
        ushort4* dst = reinterpret_cast<ushort4*>(Wmt) + (size_t)tt * 128 + lane * 2;
        dst[0] = ushort4{v[0],v[1],v[2],v[3]};
        dst[1] = ushort4{v[4],v[5],v[6],v[7]};
    }
}

// ====== conv_fused v3: 1 batch/block (grid 1024), 512 thr, ~17.7 KB LDS ========
// conv1 K-split in two E-halves. xs rows 512B: emb half (34 rows) ->
// y1 (18 rows) -> y2 (9 rows x 640B).
__global__ __launch_bounds__(512, 4) void conv_fused(
    const int* __restrict__ sent, const float* __restrict__ emb,
    const unsigned short* __restrict__ W1t, const float* __restrict__ b1,
    const unsigned short* __restrict__ W2t, const float* __restrict__ b2,
    const unsigned short* __restrict__ W3t, const float* __restrict__ b3,
    const float* __restrict__ image, unsigned short* __restrict__ feats)
{
    const int bat = blockIdx.x;            // one batch
    const int tid = threadIdx.x;
    __shared__ unsigned short xs[34 * 256];   // 17,408 B
    __shared__ float rs[32];
    __shared__ float rs2[18];
    __shared__ float rs3[9];
    char* xsb = reinterpret_cast<char*>(xs);

    const int wid = tid >> 6, lane = tid & 63;
    const int kg = lane >> 4, trow = lane & 15, g = kg;

    const bf16x8* wb1 = reinterpret_cast<const bf16x8*>(W1t);
    const bf16x8* wp0 = wb1 + (size_t)((wid    ) * KT1) * 64 + lane;
    const bf16x8* wp1 = wb1 + (size_t)((wid + 8) * KT1) * 64 + lane;

    // c<nt><mt>: 2 nt x 2 M-tiles (waves 5-7 use only c0x)
    f32x4 c00={0,0,0,0},c01={0,0,0,0};
    f32x4 c10={0,0,0,0},c11={0,0,0,0};

    // ---- Phase 1+2: two E-halves; stage 256 cols of 30 rows, then 24 K-steps --
    #pragma unroll
    for (int h = 0; h < 2; ++h) {
        if (h == 1) __syncthreads();

        #pragma unroll
        for (int r8 = 0; r8 < 4; ++r8) {
            int R = wid + 8 * r8;
            if (R < 30) {
                int row = sent[bat * PAD + R];
                float4 e = reinterpret_cast<const float4*>(
                    emb + (size_t)row * E + h * 256)[lane];
                float sum = e.x + e.y + e.z + e.w;
                ushort4 pk4{f2bf(e.x), f2bf(e.y), f2bf(e.z), f2bf(e.w)};
                int c = lane >> 1;
                int bo = R * 512 + ((c ^ (R & 7)) << 4) + (lane & 1) * 8;
                *reinterpret_cast<ushort4*>(xsb + bo) = pk4;
                for (int off = 32; off; off >>= 1) sum += __shfl_down(sum, off);
                if (lane == 0) { if (h == 0) rs[R] = sum; else rs[R] += sum; }
            }
        }
        // zero pad rows 30..33 (this half's 512B per row)
        if (tid < 256) {
            int R = 30 + (tid >> 6);
            int c = lane >> 1;
            int bo = R * 512 + ((c ^ (R & 7)) << 4) + (lane & 1) * 8;
            *reinterpret_cast<ushort4*>(xsb + bo) = ushort4{0,0,0,0};
        }
        if (h == 0 && tid < 2) rs[30 + tid] = 0.f;
        __syncthreads();

        // conv1 K-steps: kk = rowoff*16 + h*8 + cc
        if (wid < 5) {
            #pragma unroll
            for (int rowoff = 0; rowoff < 3; ++rowoff) {
                const int R0 = trow + rowoff;
                const int R1 = R0 + 16;
                #pragma unroll
                for (int cc = 0; cc < 8; ++cc) {
                    const int kk = rowoff * 16 + h * 8 + cc;
                    const int ch2 = cc * 4 + kg;
                    bf16x8 a0 = *reinterpret_cast<const bf16x8*>(
                        xsb + R0 * 512 + ((ch2 ^ (R0 & 7)) << 4));
                    bf16x8 a1 = *reinterpret_cast<const bf16x8*>(
                        xsb + R1 * 512 + ((ch2 ^ (R1 & 7)) << 4));
                    bf16x8 b0 = wp0[kk * 64];
                    bf16x8 b1v = wp1[kk * 64];
                    c00 = __builtin_amdgcn_mfma_f32_16x16x32_bf16(a0, b0, c00, 0, 0, 0);
                    c01 = __builtin_amdgcn_mfma_f32_16x16x32_bf16(a1, b0, c01, 0, 0, 0);
                    c10 = __builtin_amdgcn_mfma_f32_16x16x32_bf16(a0, b1v, c10, 0, 0, 0);
                    c11 = __builtin_amdgcn_mfma_f32_16x16x32_bf16(a1, b1v, c11, 0, 0, 0);
                }
            }
        } else {
            #pragma unroll
            for (int rowoff = 0; rowoff < 3; ++rowoff) {
                const int R0 = trow + rowoff;
                const int R1 = R0 + 16;
                #pragma unroll
                for (int cc = 0; cc < 8; ++cc) {
                    const int kk = rowoff * 16 + h * 8 + cc;
                    const int ch2 = cc * 4 + kg;
                    bf16x8 a0 = *reinterpret_cast<const bf16x8*>(
                        xsb + R0 * 512 + ((ch2 ^ (R0 & 7)) << 4));
                    bf16x8 a1 = *reinterpret_cast<const bf16x8*>(
                        xsb + R1 * 512 + ((ch2 ^ (R1 & 7)) << 4));
                    bf16x8 b0 = wp0[kk * 64];
                    c00 = __builtin_amdgcn_mfma_f32_16x16x32_bf16(a0, b0, c00, 0, 0, 0);
                    c01 = __builtin_amdgcn_mfma_f32_16x16x32_bf16(a1, b0, c01, 0, 0, 0);
                }
            }
        }
    }
    __syncthreads();   // emb region dead

    // ---- Phase 3: zero y1 region (18 rows x 512B) ----
    for (int idx = tid; idx < 18 * 32; idx += 512) {
        int r = idx >> 5, ck = idx & 31;
        union { ushort4 u4[2]; bf16x8 v; } pk;
        pk.u4[0] = ushort4{0,0,0,0}; pk.u4[1] = ushort4{0,0,0,0};
        *reinterpret_cast<bf16x8*>(xsb + r * 512 + (ck << 4)) = pk.v;
    }
    __syncthreads();

    // ---- Phase 4: conv1 epilogue -> y1 LDS (bf16, conv2-swizzled) ----
#define EPIM1(MT, CM) do {                                                       \
    int mloc = (MT) * 16;                                                        \
    _Pragma("unroll")                                                            \
    for (int hf = 0; hf < 2; ++hf) {                                             \
        int wl = mloc + 4 * g + 2 * hf;                                          \
        int tp = wl >> 1;                                                        \
        if (tp < 14) {                                                           \
            float v0 = CM[2*hf] + bia, v1 = CM[2*hf+1] + bia;                    \
            v0 = LEAKY(v0); v1 = LEAKY(v1);                                      \
            if (rs[wl] + rs[wl+1] + rs[wl+2] == 0.f) v0 = 0.f;                   \
            if (rs[wl+1] + rs[wl+2] + rs[wl+3] == 0.f) v1 = 0.f;                 \
            int rg = tp;                                                         \
            int bo = rg * 512 + ((((ch) >> 3) ^ (rg & 7)) << 4) + ((ch) & 7) * 2;\
            *reinterpret_cast<unsigned short*>(xsb + bo) = f2bf(fmaxf(v0, v1));  \
        }                                                                        \
    }                                                                            \
} while (0)

#define EPI1(NTI, CA, CB) do {                                                   \
    int ch = (wid + 8 * (NTI)) * 16 + trow;                                      \
    if (ch < C1) {                                                               \
        float bia = b1[ch];                                                      \
        EPIM1(0, CA); EPIM1(1, CB);                                              \
    }                                                                            \
} while (0)

    EPI1(0, c00, c01);
    if (wid < 5) {
        EPI1(1, c10, c11);
    }
#undef EPI1
#undef EPIM1
    __syncthreads();

    // ---- Phase 5: y1 rowsums (18 rows x 256) ----
    for (int r = wid; r < 18; r += 8) {
        float s = 0.f;
        #pragma unroll
        for (int j = 0; j < 4; ++j) {
            int e = lane + 64 * j;
            int chunk = e >> 3, within = e & 7;
            s += bf2f(*reinterpret_cast<unsigned short*>(
                xsb + r * 512 + ((chunk ^ (r & 7)) << 4) + within * 2));
        }
        for (int off = 32; off; off >>= 1) s += __shfl_down(s, off);
        if (lane == 0) rs2[r] = s;
    }
    __syncthreads();

    // ---- Phase 6: conv2 K-loop (8 waves x {w, w+8, clamp} nt x 1 M-tile) ----
    const bf16x8* wb2 = reinterpret_cast<const bf16x8*>(W2t);
    const int nt2a = wid, nt2b = wid + 8;
    const int nt2c = (wid + 16 < NT2P) ? (wid + 16) : (NT2P - 1);
    const bf16x8* q0 = wb2 + (size_t)(nt2a * KT2) * 64 + lane;
    const bf16x8* q1 = wb2 + (size_t)(nt2b * KT2) * 64 + lane;
    const bf16x8* q2 = wb2 + (size_t)(nt2c * KT2) * 64 + lane;

    f32x4 d0={0,0,0,0},d1={0,0,0,0},d2={0,0,0,0};

    {
        int kidx = 0;
        #pragma unroll
        for (int rowoff = 0; rowoff < 3; ++rowoff) {
            const int R0 = trow + rowoff;
            const int b3_0 = R0 * 512 + (((R0 & 7) ^ kg) << 4);
            #pragma unroll
            for (int cc = 0; cc < 7; ++cc, ++kidx) {
                bf16x8 a0 = *reinterpret_cast<const bf16x8*>(xsb + (b3_0 ^ (cc << 6)));
                bf16x8 b0 = q0[kidx * 64];
                bf16x8 b1v = q1[kidx * 64];
                bf16x8 b2v = q2[kidx * 64];
                d0 = __builtin_amdgcn_mfma_f32_16x16x32_bf16(a0, b0,  d0, 0, 0, 0);
                d1 = __builtin_amdgcn_mfma_f32_16x16x32_bf16(a0, b1v, d1, 0, 0, 0);
                d2 = __builtin_amdgcn_mfma_f32_16x16x32_bf16(a0, b2v, d2, 0, 0, 0);
            }
        }
    }
    __syncthreads();   // y1 region dead

    // ---- Phase 7: zero y2 region (9 rows x 640B) ----
    for (int idx = tid; idx < 9 * 40; idx += 512) {
        int r = idx / 40, ck = idx % 40;
        union { ushort4 u4[2]; bf16x8 v; } pk;
        pk.u4[0] = ushort4{0,0,0,0}; pk.u4[1] = ushort4{0,0,0,0};
        *reinterpret_cast<bf16x8*>(xsb + r * 640 + (ck << 4)) = pk.v;
    }
    __syncthreads();

    // ---- Phase 8: conv2 epilogue -> y2 LDS (bf16, conv3-swizzled) ----
#define EPI2F(NT, DM) do {                                                       \
    int ch = (NT) * 16 + trow;                                                   \
    if (ch < C2) {                                                               \
        float bia = b2[ch];                                                      \
        _Pragma("unroll")                                                        \
        for (int hf = 0; hf < 2; ++hf) {                                         \
            int t0 = 4 * g + 2 * hf;                                             \
            if (t0 < 12) {                                                       \
                float v0 = LEAKY(DM[2*hf]   + bia);                              \
                float v1 = LEAKY(DM[2*hf+1] + bia);                              \
                if (rs2[t0] + rs2[t0+1] + rs2[t0+2] == 0.f) v0 = 0.f;            \
                if (rs2[t0+1] + rs2[t0+2] + rs2[t0+3] == 0.f) v1 = 0.f;          \
                int rg = (t0 >> 1);                                              \
                int bo = rg * 640 + ((((ch)>>3) ^ (rg & 7)) << 4) + ((ch)&7)*2;  \
                *reinterpret_cast<unsigned short*>(xsb + bo) = f2bf(fmaxf(v0, v1)); \
            }                                                                    \
        }                                                                        \
    }                                                                            \
} while (0)

    EPI2F(nt2a, d0);
    EPI2F(nt2b, d1);
    EPI2F(nt2c, d2);
#undef EPI2F
    __syncthreads();

    // ---- Phase 9: y2 rowsums (6 real rows x 320) ----
    if (wid < 6) {
        int r = wid;
        float s = 0.f;
        #pragma unroll
        for (int j = 0; j < 5; ++j) {
            int e = lane + 64 * j;
            int chunk = e >> 3, within = e & 7;
            s += bf2f(*reinterpret_cast<unsigned short*>(
                xsb + r * 640 + ((chunk ^ (r & 7)) << 4) + within * 2));
        }
        for (int off = 32; off; off >>= 1) s += __shfl_down(s, off);
        if (lane == 0) rs3[r] = s;
    }
    if (tid >= 384 && tid < 387) rs3[6 + (tid - 384)] = 0.f;
    __syncthreads();

    // ---- Phase 10: conv3 K-loop (M rows 0-3 = windows; lanes trow>=4 pad) ----
    const int rbase = (trow < 4) ? trow : 6;

    const bf16x8* wb3 = reinterpret_cast<const bf16x8*>(W3t);
    const int nt3a = wid, nt3b = wid + 8;
    const int nt3c = (wid < 3) ? (wid + 16) : 19;
    const bf16x8* p0 = wb3 + (size_t)(nt3a * KT3) * 64 + lane;
    const bf16x8* p1 = wb3 + (size_t)(nt3b * KT3) * 64 + lane;
    const bf16x8* p2 = wb3 + (size_t)(nt3c * KT3) * 64 + lane;

    f32x4 e0={0,0,0,0},e1={0,0,0,0},e2={0,0,0,0};

    {
        int kidx = 0;
        #pragma unroll
        for (int rowoff = 0; rowoff < 3; ++rowoff) {
            const int R0 = rbase + rowoff;
            #pragma unroll
            for (int cc = 0; cc < 10; ++cc, ++kidx) {
                int chunk = cc * 4 + kg;
                bf16x8 a0 = *reinterpret_cast<const bf16x8*>(
                    xsb + R0 * 640 + ((chunk ^ (R0 & 7)) << 4));
                bf16x8 b0 = p0[kidx * 64];
                bf16x8 b1v = p1[kidx * 64];
                bf16x8 b2v = p2[kidx * 64];
                e0 = __builtin_amdgcn_mfma_f32_16x16x32_bf16(a0, b0,  e0, 0, 0, 0);
                e1 = __builtin_amdgcn_mfma_f32_16x16x32_bf16(a0, b1v, e1, 0, 0, 0);
                e2 = __builtin_amdgcn_mfma_f32_16x16x32_bf16(a0, b2v, e2, 0, 0, 0);
            }
        }
    }

    // ---- Phase 11: conv3 epilogue -> feats. g==0 holds windows 0..3 in regs ---
#define EPI3F(NT, EM) do {                                                       \
    int ch = (NT) * 16 + trow;                                                   \
    if (ch < C3 && g == 0) {                                                     \
        float bia = b3[ch];                                                      \
        _Pragma("unroll")                                                        \
        for (int tp = 0; tp < 2; ++tp) {                                         \
            int rb = 2 * tp;                                                     \
            float v0 = LEAKY(EM[2*tp]   + bia);                                  \
            float v1 = LEAKY(EM[2*tp+1] + bia);                                  \
            if (rs3[rb] + rs3[rb+1] + rs3[rb+2] == 0.f) v0 = 0.f;                \
            if (rs3[rb+1] + rs3[rb+2] + rs3[rb+3] == 0.f) v1 = 0.f;              \
            feats[(size_t)bat * FK + tp * C3 + ch] = f2bf(fmaxf(v0, v1));        \
        }                                                                        \
    }                                                                            \
} while (0)

    EPI3F(nt3a, e0);
    EPI3F(nt3b, e1);
    EPI3F(nt3c, e2);
#undef EPI3F

    // ---- Phase 12: image -> feats bf16 (cols 600..2647) + pad (2648..2655) ----
    if (tid < 257) {
        if (tid < 256) {
            const float4* src = reinterpret_cast<const float4*>(
                image + (size_t)bat * IMG + tid * 8);
            float4 a = src[0], d = src[1];
            ushort4* dst = reinterpret_cast<ushort4*>(feats + (size_t)bat * FK + 600 + tid * 8);
            dst[0] = ushort4{f2bf(a.x),f2bf(a.y),f2bf(a.z),f2bf(a.w)};
            dst[1] = ushort4{f2bf(d.x),f2bf(d.y),f2bf(d.z),f2bf(d.w)};
        } else {
            ushort4* dst = reinterpret_cast<ushort4*>(feats + (size_t)bat * FK + 2648);
            dst[0] = ushort4{0,0,0,0};
            dst[1] = ushort4{0,0,0,0};
        }
    }
}

// ====== final GEMM: 224 blocks x 4 waves; wave = (mt, 2 nt), depth-2 prefetch ==
__global__ __launch_bounds__(256) void final_mfma(
    const unsigned short* __restrict__ feats, const unsigned short* __restrict__ Wmt,
    const float* __restrict__ bm, float* __restrict__ h)
{
    const int tid = threadIdx.x;
    const int wid = tid >> 6, lane = tid & 63;
    const int gw = blockIdx.x * 4 + wid;          // 0..895
    const int mt = gw / 14, q = gw % 14;
    const int kg = lane >> 4, trow = lane & 15, g = kg;
    const int m0 = mt * 16;

    const bf16x8* ap = reinterpret_cast<const bf16x8*>(feats)
                       + (size_t)(m0 + trow) * (FK / 8) + kg;
    const bf16x8* wb = reinterpret_cast<const bf16x8*>(Wmt);
    const bf16x8* wp0 = wb + (size_t)((q     ) * KTM) * 64 + lane;
    const bf16x8* wp1 = wb + (size_t)((q + 14) * KTM) * 64 + lane;

    f32x4 c0 = {0,0,0,0}, c1 = {0,0,0,0};

    bf16x8 aA = ap[0],     aB = ap[4];
    bf16x8 b0A = wp0[0],   b1A = wp1[0];
    bf16x8 b0B = wp0[64],  b1B = wp1[64];
    for (int kk = 0; kk < KTM - 2; ++kk) {
        bf16x8 a = aA, b0 = b0A, b1 = b1A;
        aA = aB; b0A = b0B; b1A = b1B;
        aB  = ap [(kk + 2) * 4];
        b0B = wp0[(kk + 2) * 64];
        b1B = wp1[(kk + 2) * 64];
        c0 = __builtin_amdgcn_mfma_f32_16x16x32_bf16(a, b0, c0, 0, 0, 0);
        c1 = __builtin_amdgcn_mfma_f32_16x16x32_bf16(a, b1, c1, 0, 0, 0);
    }
    c0 = __builtin_amdgcn_mfma_f32_16x16x32_bf16(aA, b0A, c0, 0, 0, 0);
    c1 = __builtin_amdgcn_mfma_f32_16x16x32_bf16(aA, b1A, c1, 0, 0, 0);
    c0 = __builtin_amdgcn_mfma_f32_16x16x32_bf16(aB, b0B, c0, 0, 0, 0);
    c1 = __builtin_amdgcn_mfma_f32_16x16x32_bf16(aB, b1B, c1, 0, 0, 0);

#define EPIM(NT, CM) do {                                                        \
    int ch = (NT) * 16 + trow;                                                   \
    if (ch < LIN2) {                                                             \
        float bia = bm[ch];                                                      \
        _Pragma("unroll")                                                        \
        for (int reg = 0; reg < 4; ++reg) {                                      \
            float v = LEAKY(CM[reg] + bia);                                      \
            h[(size_t)(m0 + 4 * g + reg) * LIN2 + ch] = v;                       \
        }                                                                        \
    }                                                                            \
} while (0)

    EPIM(q,      c0);
    EPIM(q + 14, c1);
#undef EPIM
}

// ====== out[b] = h[b] . Wo + bo ================================================
__global__ __launch_bounds__(256) void final_reduce(
    const float* __restrict__ h, const float* __restrict__ Wo,
    const float* __restrict__ bo, float* __restrict__ out)
{
    const int tid = threadIdx.x;
    const int wid = tid >> 6, lane = tid & 63;
    const int b = blockIdx.x * 4 + wid;
    float s = 0.f;
    #pragma unroll
    for (int j = 0; j < 7; ++j) {
        int o = lane + 64 * j;
        if (o < LIN2) s += h[(size_t)b * LIN2 + o] * Wo[o];
    }
    for (int off = 32; off; off >>= 1) s += __shfl_down(s, off);
    if (lane == 0) out[b] = s + bo[0];
}

extern "C" void kernel_launch(void* const* d_in, const int* in_sizes, int n_in,
                              void* d_out, int out_size, void* d_ws, size_t ws_size,
                              hipStream_t stream) {
    const float* image = (const float*)d_in[0];
    const int*   sent  = (const int*)  d_in[1];
    const float* emb   = (const float*)d_in[2];
    const float* W1    = (const float*)d_in[3];
    const float* b1    = (const float*)d_in[4];
    const float* W2    = (const float*)d_in[5];
    const float* b2    = (const float*)d_in[6];
    const float* W3    = (const float*)d_in[7];
    const float* b3    = (const float*)d_in[8];
    const float* Wm    = (const float*)d_in[9];
    const float* bm    = (const float*)d_in[10];
    const float* Wo    = (const float*)d_in[11];
    const float* bo    = (const float*)d_in[12];
    float* out = (float*)d_out;

    // ws layout — all regions disjoint, single writer each, rewritten every call
    unsigned short* W1t = (unsigned short*)d_ws;
    unsigned short* W2t = W1t + (size_t)T1 * 512;
    unsigned short* W3t = W2t + (size_t)T2 * 512;
    unsigned short* Wmt = W3t + (size_t)T3 * 512;
    unsigned short* feats = Wmt + (size_t)TM * 512;      // B_*FK bf16
    float* h = (float*)(feats + (size_t)B_ * FK);        // B_*LIN2 f32

    convert_all<<<(TTOT * 64 + 255) / 256, 256, 0, stream>>>(
        W1, W2, W3, Wm, W1t, W2t, W3t, Wmt);

    conv_fused<<<B_, 512, 0, stream>>>(
        sent, emb, W1t, b1, W2t, b2, W3t, b3, image, feats);

    final_mfma<<<224, 256, 0, stream>>>(feats, Wmt, bm, h);
    final_reduce<<<B_ / 4, 256, 0, stream>>>(h, Wo, bo, out);
}

// Round 16
// 98.511 us; speedup vs baseline: 1.3082x; 1.3082x over previous
//
#include <hip/hip_runtime.h>
#include <hip/hip_bf16.h>

#define LEAKY(v) ((v) > 0.0f ? (v) : 0.01f * (v))

constexpr int B_   = 1024;
constexpr int PAD  = 30;
constexpr int E    = 512;
constexpr int IMG  = 2048;
constexpr int C1   = 200;
constexpr int C2   = 300;
constexpr int C3   = 300;
constexpr int LIN2 = 400;

constexpr int NT1P = 16, KT1 = 48;
constexpr int NT2P = 20, KT2 = 21;
constexpr int NT3P = 24, KT3 = 30;
constexpr int NTMP = 28, KTM = 83;
constexpr int FK  = 2656;

constexpr int T1 = NT1P * KT1;       // 768
constexpr int T2 = NT2P * KT2;       // 420
constexpr int T3 = NT3P * KT3;       // 720
constexpr int TM = NTMP * KTM;       // 2324
constexpr int TTOT = T1 + T2 + T3 + TM;

typedef __attribute__((ext_vector_type(8))) short bf16x8;
typedef __attribute__((ext_vector_type(4))) float f32x4;

__device__ inline unsigned short f2bf(float f) {
    __hip_bfloat16 h = __float2bfloat16(f);
    return *reinterpret_cast<unsigned short*>(&h);
}
__device__ inline float bf2f(unsigned short u) {
    unsigned int b = ((unsigned int)u) << 16;
    return __uint_as_float(b);
}

// ================= fused weight converter (unchanged, verified) =================
__global__ __launch_bounds__(256) void convert_all(
    const float* __restrict__ W1, const float* __restrict__ W2,
    const float* __restrict__ W3, const float* __restrict__ Wm,
    unsigned short* __restrict__ W1t, unsigned short* __restrict__ W2t,
    unsigned short* __restrict__ W3t, unsigned short* __restrict__ Wmt)
{
    int idx = blockIdx.x * 256 + threadIdx.x;
    if (idx >= TTOT * 64) return;
    int lane = idx & 63, t = idx >> 6;
    unsigned short v[8];

    if (t < T1) {
        int kk = t % KT1, nt = t / KT1;
        int ch = nt * 16 + (lane & 15);
        int k0 = kk * 32 + (lane >> 4) * 8;
        #pragma unroll
        for (int j = 0; j < 8; ++j)
            v[j] = (ch < C1) ? f2bf(W1[(size_t)ch * (3*E) + k0 + j]) : (unsigned short)0;
        ushort4* dst = reinterpret_cast<ushort4*>(W1t) + (size_t)t * 128 + lane * 2;
        dst[0] = ushort4{v[0],v[1],v[2],v[3]};
        dst[1] = ushort4{v[4],v[5],v[6],v[7]};
    } else if (t < T1 + T2) {
        int tt = t - T1;
        int kk = tt % KT2, nt = tt / KT2;
        int ch = nt * 16 + (lane & 15);
        int rowoff = kk / 7;
        int cbase  = (kk % 7) * 32 + (lane >> 4) * 8;
        #pragma unroll
        for (int j = 0; j < 8; ++j) {
            int c = cbase + j;
            v[j] = (ch < C2 && c < C1) ? f2bf(W2[(size_t)ch * (3*C1) + rowoff * C1 + c])
                                       : (unsigned short)0;
        }
        ushort4* dst = reinterpret_cast<ushort4*>(W2t) + (size_t)tt * 128 + lane * 2;
        dst[0] = ushort4{v[0],v[1],v[2],v[3]};
        dst[1] = ushort4{v[4],v[5],v[6],v[7]};
    } else if (t < T1 + T2 + T3) {
        int tt = t - T1 - T2;
        int kk = tt % KT3, nt = tt / KT3;
        int ch = nt * 16 + (lane & 15);
        int rowoff = kk / 10;
        int cbase  = (kk % 10) * 32 + (lane >> 4) * 8;
        #pragma unroll
        for (int j = 0; j < 8; ++j) {
            int c = cbase + j;
            v[j] = (ch < C3 && c < C2) ? f2bf(W3[(size_t)ch * (3*C2) + rowoff * C2 + c])
                                       : (unsigned short)0;
        }
        ushort4* dst = reinterpret_cast<ushort4*>(W3t) + (size_t)tt * 128 + lane * 2;
        dst[0] = ushort4{v[0],v[1],v[2],v[3]};
        dst[1] = ushort4{v[4],v[5],v[6],v[7]};
    } else {
        int tt = t - T1 - T2 - T3;
        int kk = tt % KTM, nt = tt / KTM;
        int ch = nt * 16 + (lane & 15);
        int kbase = kk * 32 + (lane >> 4) * 8;
        #pragma unroll
        for (int j = 0; j < 8; ++j) {
            int k = kbase + j;
            v[j] = (ch < LIN2 && k < 2648) ? f2bf(Wm[(size_t)ch * 2648 + k])
                                           : (unsigned short)0;
        }
        ushort4* dst = reinterpret_cast<ushort4*>(Wmt) + (size_t)tt * 128 + lane * 2;
        dst[0] = ushort4{v[0],v[1],v[2],v[3]};
        dst[1] = ushort4{v[4],v[5],v[6],v[7]};
    }
}

// ====== conv_fused v2: conv1(K-split halves)+conv2+conv3+concat, 2 batches/blk ==
// 512 blocks x 512 thr. LDS ~34.3 KB.
__global__ __launch_bounds__(512, 4) void conv_fused(
    const int* __restrict__ sent, const float* __restrict__ emb,
    const unsigned short* __restrict__ W1t, const float* __restrict__ b1,
    const unsigned short* __restrict__ W2t, const float* __restrict__ b2,
    const unsigned short* __restrict__ W3t, const float* __restrict__ b3,
    const float* __restrict__ image, unsigned short* __restrict__ feats)
{
    const int blk = blockIdx.x;            // batches 2*blk, 2*blk+1
    const int tid = threadIdx.x;
    __shared__ unsigned short xs[66 * 256];   // 33,792 B
    __shared__ float rs[64];
    __shared__ float rs2[36];
    __shared__ float rs3[12];
    char* xsb = reinterpret_cast<char*>(xs);

    const int wid = tid >> 6, lane = tid & 63;
    const int kg = lane >> 4, trow = lane & 15, g = kg;

    const bf16x8* wb1 = reinterpret_cast<const bf16x8*>(W1t);
    const bf16x8* wp0 = wb1 + (size_t)((wid    ) * KT1) * 64 + lane;
    const bf16x8* wp1 = wb1 + (size_t)((wid + 8) * KT1) * 64 + lane;

    f32x4 c00={0,0,0,0},c01={0,0,0,0},c02={0,0,0,0},c03={0,0,0,0};
    f32x4 c10={0,0,0,0},c11={0,0,0,0},c12={0,0,0,0},c13={0,0,0,0};

    // ---- Phase 1+2: two E-halves; stage 256 cols of all rows, then 24 K-steps --
    #pragma unroll
    for (int h = 0; h < 2; ++h) {
        if (h == 1) __syncthreads();   // protect half-0 reads before overwrite

        #pragma unroll
        for (int r8 = 0; r8 < 8; ++r8) {
            int r = wid + 8 * r8;
            if (r < 60) {
                int bl = r / 30, rr = r % 30;
                int R = bl * 32 + rr;
                int row = sent[(2 * blk + bl) * PAD + rr];
                float4 e = reinterpret_cast<const float4*>(
                    emb + (size_t)row * E + h * 256)[lane];
                float sum = e.x + e.y + e.z + e.w;
                ushort4 pk4{f2bf(e.x), f2bf(e.y), f2bf(e.z), f2bf(e.w)};
                int c = lane >> 1;
                int bo = R * 512 + ((c ^ (R & 7)) << 4) + (lane & 1) * 8;
                *reinterpret_cast<ushort4*>(xsb + bo) = pk4;
                for (int off = 32; off; off >>= 1) sum += __shfl_down(sum, off);
                if (lane == 0) { if (h == 0) rs[R] = sum; else rs[R] += sum; }
            }
        }
        // zero pad rows 30,31,62,63,64,65 (this half's 512B per row)
        if (tid < 384) {
            int zi = tid >> 6;
            int R = (zi < 2) ? (30 + zi) : (60 + zi);
            int c = lane >> 1;
            int bo = R * 512 + ((c ^ (R & 7)) << 4) + (lane & 1) * 8;
            *reinterpret_cast<ushort4*>(xsb + bo) = ushort4{0,0,0,0};
        }
        if (h == 0 && tid < 4) {
            const int pr[4] = {30, 31, 62, 63};
            rs[pr[tid]] = 0.f;
        }
        __syncthreads();

        // conv1 K-steps touching this half: kk = rowoff*16 + h*8 + cc, cc 0..7
        if (wid < 5) {
            #pragma unroll
            for (int rowoff = 0; rowoff < 3; ++rowoff) {
                const int R0 = trow + rowoff;
                const int R1 = R0 + 16, R2 = R0 + 32, R3 = R0 + 48;
                #pragma unroll
                for (int cc = 0; cc < 8; ++cc) {
                    const int kk = rowoff * 16 + h * 8 + cc;
                    const int ch2 = cc * 4 + kg;
                    bf16x8 a0 = *reinterpret_cast<const bf16x8*>(
                        xsb + R0 * 512 + (((ch2) ^ (R0 & 7)) << 4));
                    bf16x8 a1 = *reinterpret_cast<const bf16x8*>(
                        xsb + R1 * 512 + (((ch2) ^ (R1 & 7)) << 4));
                    bf16x8 a2 = *reinterpret_cast<const bf16x8*>(
                        xsb + R2 * 512 + (((ch2) ^ (R2 & 7)) << 4));
                    bf16x8 a3 = *reinterpret_cast<const bf16x8*>(
                        xsb + R3 * 512 + (((ch2) ^ (R3 & 7)) << 4));
                    bf16x8 b0 = wp0[kk * 64];
                    bf16x8 b1v = wp1[kk * 64];
                    c00 = __builtin_amdgcn_mfma_f32_16x16x32_bf16(a0, b0, c00, 0, 0, 0);
                    c01 = __builtin_amdgcn_mfma_f32_16x16x32_bf16(a1, b0, c01, 0, 0, 0);
                    c02 = __builtin_amdgcn_mfma_f32_16x16x32_bf16(a2, b0, c02, 0, 0, 0);
                    c03 = __builtin_amdgcn_mfma_f32_16x16x32_bf16(a3, b0, c03, 0, 0, 0);
                    c10 = __builtin_amdgcn_mfma_f32_16x16x32_bf16(a0, b1v, c10, 0, 0, 0);
                    c11 = __builtin_amdgcn_mfma_f32_16x16x32_bf16(a1, b1v, c11, 0, 0, 0);
                    c12 = __builtin_amdgcn_mfma_f32_16x16x32_bf16(a2, b1v, c12, 0, 0, 0);
                    c13 = __builtin_amdgcn_mfma_f32_16x16x32_bf16(a3, b1v, c13, 0, 0, 0);
                }
            }
        } else {
            #pragma unroll
            for (int rowoff = 0; rowoff < 3; ++rowoff) {
                const int R0 = trow + rowoff;
                const int R1 = R0 + 16, R2 = R0 + 32, R3 = R0 + 48;
                #pragma unroll
                for (int cc = 0; cc < 8; ++cc) {
                    const int kk = rowoff * 16 + h * 8 + cc;
                    const int ch2 = cc * 4 + kg;
                    bf16x8 a0 = *reinterpret_cast<const bf16x8*>(
                        xsb + R0 * 512 + (((ch2) ^ (R0 & 7)) << 4));
                    bf16x8 a1 = *reinterpret_cast<const bf16x8*>(
                        xsb + R1 * 512 + (((ch2) ^ (R1 & 7)) << 4));
                    bf16x8 a2 = *reinterpret_cast<const bf16x8*>(
                        xsb + R2 * 512 + (((ch2) ^ (R2 & 7)) << 4));
                    bf16x8 a3 = *reinterpret_cast<const bf16x8*>(
                        xsb + R3 * 512 + (((ch2) ^ (R3 & 7)) << 4));
                    bf16x8 b0 = wp0[kk * 64];
                    c00 = __builtin_amdgcn_mfma_f32_16x16x32_bf16(a0, b0, c00, 0, 0, 0);
                    c01 = __builtin_amdgcn_mfma_f32_16x16x32_bf16(a1, b0, c01, 0, 0, 0);
                    c02 = __builtin_amdgcn_mfma_f32_16x16x32_bf16(a2, b0, c02, 0, 0, 0);
                    c03 = __builtin_amdgcn_mfma_f32_16x16x32_bf16(a3, b0, c03, 0, 0, 0);
                }
            }
        }
    }
    __syncthreads();   // emb region dead

    // ---- Phase 3: zero y1 region (36 rows x 512B) ----
    for (int idx = tid; idx < 36 * 32; idx += 512) {
        int r = idx >> 5, ck = idx & 31;
        union { ushort4 u4[2]; bf16x8 v; } pk;
        pk.u4[0] = ushort4{0,0,0,0}; pk.u4[1] = ushort4{0,0,0,0};
        *reinterpret_cast<bf16x8*>(xsb + r * 512 + (ck << 4)) = pk.v;
    }
    __syncthreads();

    // ---- Phase 4: conv1 epilogue -> y1 LDS (bf16, conv2-swizzled) ----
#define EPIM1(MT, CM) do {                                                       \
    int bl = (MT) >> 1;                                                          \
    int mloc = ((MT) & 1) * 16;                                                  \
    _Pragma("unroll")                                                            \
    for (int hf = 0; hf < 2; ++hf) {                                             \
        int wl = mloc + 4 * g + 2 * hf;                                          \
        int tp = wl >> 1;                                                        \
        if (tp < 14) {                                                           \
            float v0 = CM[2*hf] + bia, v1 = CM[2*hf+1] + bia;                    \
            v0 = LEAKY(v0); v1 = LEAKY(v1);                                      \
            int rb = bl * 32 + wl;                                               \
            if (rs[rb] + rs[rb+1] + rs[rb+2] == 0.f) v0 = 0.f;                   \
            if (rs[rb+1] + rs[rb+2] + rs[rb+3] == 0.f) v1 = 0.f;                 \
            int rg = bl * 18 + tp;                                               \
            int bo = rg * 512 + ((((ch) >> 3) ^ (rg & 7)) << 4) + ((ch) & 7) * 2;\
            *reinterpret_cast<unsigned short*>(xsb + bo) = f2bf(fmaxf(v0, v1));  \
        }                                                                        \
    }                                                                            \
} while (0)

#define EPI1(NTI, CA, CB, CC, CD) do {                                           \
    int ch = (wid + 8 * (NTI)) * 16 + trow;                                      \
    if (ch < C1) {                                                               \
        float bia = b1[ch];                                                      \
        EPIM1(0, CA); EPIM1(1, CB); EPIM1(2, CC); EPIM1(3, CD);                  \
    }                                                                            \
} while (0)

    EPI1(0, c00, c01, c02, c03);
    if (wid < 5) {
        EPI1(1, c10, c11, c12, c13);
    }
#undef EPI1
#undef EPIM1
    __syncthreads();

    // ---- Phase 5: y1 rowsums (36 rows x 256) ----
    for (int r = wid; r < 36; r += 8) {
        float s = 0.f;
        #pragma unroll
        for (int j = 0; j < 4; ++j) {
            int e = lane + 64 * j;
            int chunk = e >> 3, within = e & 7;
            s += bf2f(*reinterpret_cast<unsigned short*>(
                xsb + r * 512 + ((chunk ^ (r & 7)) << 4) + within * 2));
        }
        for (int off = 32; off; off >>= 1) s += __shfl_down(s, off);
        if (lane == 0) rs2[r] = s;
    }
    __syncthreads();

    // ---- Phase 6: conv2 K-loop (8 waves x {w, w+8, clamp} nt x 2 batch) ----
    const bf16x8* wb2 = reinterpret_cast<const bf16x8*>(W2t);
    const int nt2a = wid, nt2b = wid + 8;
    const int nt2c = (wid + 16 < NT2P) ? (wid + 16) : (NT2P - 1);
    const bf16x8* q0 = wb2 + (size_t)(nt2a * KT2) * 64 + lane;
    const bf16x8* q1 = wb2 + (size_t)(nt2b * KT2) * 64 + lane;
    const bf16x8* q2 = wb2 + (size_t)(nt2c * KT2) * 64 + lane;

    f32x4 d00={0,0,0,0},d01={0,0,0,0};
    f32x4 d10={0,0,0,0},d11={0,0,0,0};
    f32x4 d20={0,0,0,0},d21={0,0,0,0};

    {
        int kidx = 0;
        #pragma unroll
        for (int rowoff = 0; rowoff < 3; ++rowoff) {
            const int R0 = trow + rowoff;
            const int R1 = R0 + 18;
            const int b3_0 = R0 * 512 + (((R0 & 7) ^ kg) << 4);
            const int b3_1 = R1 * 512 + (((R1 & 7) ^ kg) << 4);
            #pragma unroll
            for (int cc = 0; cc < 7; ++cc, ++kidx) {
                bf16x8 a0 = *reinterpret_cast<const bf16x8*>(xsb + (b3_0 ^ (cc << 6)));
                bf16x8 a1 = *reinterpret_cast<const bf16x8*>(xsb + (b3_1 ^ (cc << 6)));
                bf16x8 b0 = q0[kidx * 64];
                bf16x8 b1v = q1[kidx * 64];
                bf16x8 b2v = q2[kidx * 64];
                d00 = __builtin_amdgcn_mfma_f32_16x16x32_bf16(a0, b0,  d00, 0, 0, 0);
                d01 = __builtin_amdgcn_mfma_f32_16x16x32_bf16(a1, b0,  d01, 0, 0, 0);
                d10 = __builtin_amdgcn_mfma_f32_16x16x32_bf16(a0, b1v, d10, 0, 0, 0);
                d11 = __builtin_amdgcn_mfma_f32_16x16x32_bf16(a1, b1v, d11, 0, 0, 0);
                d20 = __builtin_amdgcn_mfma_f32_16x16x32_bf16(a0, b2v, d20, 0, 0, 0);
                d21 = __builtin_amdgcn_mfma_f32_16x16x32_bf16(a1, b2v, d21, 0, 0, 0);
            }
        }
    }
    __syncthreads();   // y1 region dead

    // ---- Phase 7: zero y2 region (15 rows x 640B) ----
    for (int idx = tid; idx < 15 * 40; idx += 512) {
        int r = idx / 40, ck = idx % 40;
        union { ushort4 u4[2]; bf16x8 v; } pk;
        pk.u4[0] = ushort4{0,0,0,0}; pk.u4[1] = ushort4{0,0,0,0};
        *reinterpret_cast<bf16x8*>(xsb + r * 640 + (ck << 4)) = pk.v;
    }
    __syncthreads();

    // ---- Phase 8: conv2 epilogue -> y2 LDS (bf16, conv3-swizzled) ----
#define EPI2F(NT, DA, DB) do {                                                   \
    int ch = (NT) * 16 + trow;                                                   \
    if (ch < C2) {                                                               \
        float bia = b2[ch];                                                      \
        _Pragma("unroll")                                                        \
        for (int hf = 0; hf < 2; ++hf) {                                         \
            int t0 = 4 * g + 2 * hf;                                             \
            if (t0 < 12) {                                                       \
                { float v0 = LEAKY(DA[2*hf]   + bia);                            \
                  float v1 = LEAKY(DA[2*hf+1] + bia);                            \
                  if (rs2[t0] + rs2[t0+1] + rs2[t0+2] == 0.f) v0 = 0.f;          \
                  if (rs2[t0+1] + rs2[t0+2] + rs2[t0+3] == 0.f) v1 = 0.f;        \
                  int rg = (t0 >> 1);                                            \
                  int bo = rg * 640 + ((((ch)>>3) ^ (rg & 7)) << 4) + ((ch)&7)*2;\
                  *reinterpret_cast<unsigned short*>(xsb + bo) = f2bf(fmaxf(v0, v1)); } \
                { float v0 = LEAKY(DB[2*hf]   + bia);                            \
                  float v1 = LEAKY(DB[2*hf+1] + bia);                            \
                  int rb = 18 + t0;                                              \
                  if (rs2[rb] + rs2[rb+1] + rs2[rb+2] == 0.f) v0 = 0.f;          \
                  if (rs2[rb+1] + rs2[rb+2] + rs2[rb+3] == 0.f) v1 = 0.f;        \
                  int rg = 6 + (t0 >> 1);                                        \
                  int bo = rg * 640 + ((((ch)>>3) ^ (rg & 7)) << 4) + ((ch)&7)*2;\
                  *reinterpret_cast<unsigned short*>(xsb + bo) = f2bf(fmaxf(v0, v1)); } \
            }                                                                    \
        }                                                                        \
    }                                                                            \
} while (0)

    EPI2F(nt2a, d00, d01);
    EPI2F(nt2b, d10, d11);
    EPI2F(nt2c, d20, d21);
#undef EPI2F
    __syncthreads();

    // ---- Phase 9: y2 rowsums (12 rows x 320) ----
    for (int r = wid; r < 12; r += 8) {
        float s = 0.f;
        #pragma unroll
        for (int j = 0; j < 5; ++j) {
            int e = lane + 64 * j;
            int chunk = e >> 3, within = e & 7;
            s += bf2f(*reinterpret_cast<unsigned short*>(
                xsb + r * 640 + ((chunk ^ (r & 7)) << 4) + within * 2));
        }
        for (int off = 32; off; off >>= 1) s += __shfl_down(s, off);
        if (lane == 0) rs3[r] = s;
    }
    __syncthreads();

    // ---- Phase 10: conv3 K-loop (M=16: 2 batches x 4 windows + pad) ----
    const int rbase = (trow < 8) ? (6 * (trow >> 2) + (trow & 3)) : 12;

    const bf16x8* wb3 = reinterpret_cast<const bf16x8*>(W3t);
    const int nt3a = wid, nt3b = wid + 8;
    const int nt3c = (wid < 3) ? (wid + 16) : 19;   // waves 0-2 own 16-18; rest pad
    const bf16x8* p0 = wb3 + (size_t)(nt3a * KT3) * 64 + lane;
    const bf16x8* p1 = wb3 + (size_t)(nt3b * KT3) * 64 + lane;
    const bf16x8* p2 = wb3 + (size_t)(nt3c * KT3) * 64 + lane;

    f32x4 e0={0,0,0,0},e1={0,0,0,0},e2={0,0,0,0};

    {
        int kidx = 0;
        #pragma unroll
        for (int rowoff = 0; rowoff < 3; ++rowoff) {
            const int R0 = rbase + rowoff;
            #pragma unroll
            for (int cc = 0; cc < 10; ++cc, ++kidx) {
                int chunk = cc * 4 + kg;
                bf16x8 a0 = *reinterpret_cast<const bf16x8*>(
                    xsb + R0 * 640 + ((chunk ^ (R0 & 7)) << 4));
                bf16x8 b0 = p0[kidx * 64];
                bf16x8 b1v = p1[kidx * 64];
                bf16x8 b2v = p2[kidx * 64];
                e0 = __builtin_amdgcn_mfma_f32_16x16x32_bf16(a0, b0,  e0, 0, 0, 0);
                e1 = __builtin_amdgcn_mfma_f32_16x16x32_bf16(a0, b1v, e1, 0, 0, 0);
                e2 = __builtin_amdgcn_mfma_f32_16x16x32_bf16(a0, b2v, e2, 0, 0, 0);
            }
        }
    }

    // ---- Phase 11: conv3 epilogue -> feats (global). reg = window, g = batch ---
#define EPI3F(NT, EM) do {                                                       \
    int ch = (NT) * 16 + trow;                                                   \
    if (ch < C3 && g < 2) {                                                      \
        float bia = b3[ch];                                                      \
        _Pragma("unroll")                                                        \
        for (int tp = 0; tp < 2; ++tp) {                                         \
            int rb = g * 6 + 2 * tp;                                             \
            float v0 = LEAKY(EM[2*tp]   + bia);                                  \
            float v1 = LEAKY(EM[2*tp+1] + bia);                                  \
            if (rs3[rb] + rs3[rb+1] + rs3[rb+2] == 0.f) v0 = 0.f;                \
            if (rs3[rb+1] + rs3[rb+2] + rs3[rb+3] == 0.f) v1 = 0.f;              \
            feats[(size_t)(2 * blk + g) * FK + tp * C3 + ch] = f2bf(fmaxf(v0, v1)); \
        }                                                                        \
    }                                                                            \
} while (0)

    EPI3F(nt3a, e0);
    EPI3F(nt3b, e1);
    EPI3F(nt3c, e2);
#undef EPI3F

    // ---- Phase 12: image -> feats bf16 (cols 600..2647) + pad (2648..2655) ----
    for (int idx = tid; idx < 2 * 257; idx += 512) {
        int bl = idx / 257, c = idx % 257;
        int b = 2 * blk + bl;
        if (c < 256) {
            const float4* src = reinterpret_cast<const float4*>(
                image + (size_t)b * IMG + c * 8);
            float4 a = src[0], d = src[1];
            ushort4* dst = reinterpret_cast<ushort4*>(feats + (size_t)b * FK + 600 + c * 8);
            dst[0] = ushort4{f2bf(a.x),f2bf(a.y),f2bf(a.z),f2bf(a.w)};
            dst[1] = ushort4{f2bf(d.x),f2bf(d.y),f2bf(d.z),f2bf(d.w)};
        } else {
            ushort4* dst = reinterpret_cast<ushort4*>(feats + (size_t)b * FK + 2648);
            dst[0] = ushort4{0,0,0,0};
            dst[1] = ushort4{0,0,0,0};
        }
    }
}

// ====== final GEMM: 224 blocks x 4 waves; wave = (mt, 2 nt), depth-2 prefetch ==
__global__ __launch_bounds__(256) void final_mfma(
    const unsigned short* __restrict__ feats, const unsigned short* __restrict__ Wmt,
    const float* __restrict__ bm, float* __restrict__ h)
{
    const int tid = threadIdx.x;
    const int wid = tid >> 6, lane = tid & 63;
    const int gw = blockIdx.x * 4 + wid;          // 0..895
    const int mt = gw / 14, q = gw % 14;
    const int kg = lane >> 4, trow = lane & 15, g = kg;
    const int m0 = mt * 16;

    const bf16x8* ap = reinterpret_cast<const bf16x8*>(feats)
                       + (size_t)(m0 + trow) * (FK / 8) + kg;
    const bf16x8* wb = reinterpret_cast<const bf16x8*>(Wmt);
    const bf16x8* wp0 = wb + (size_t)((q     ) * KTM) * 64 + lane;
    const bf16x8* wp1 = wb + (size_t)((q + 14) * KTM) * 64 + lane;

    f32x4 c0 = {0,0,0,0}, c1 = {0,0,0,0};

    bf16x8 aA = ap[0],     aB = ap[4];
    bf16x8 b0A = wp0[0],   b1A = wp1[0];
    bf16x8 b0B = wp0[64],  b1B = wp1[64];
    for (int kk = 0; kk < KTM - 2; ++kk) {
        bf16x8 a = aA, b0 = b0A, b1 = b1A;
        aA = aB; b0A = b0B; b1A = b1B;
        aB  = ap [(kk + 2) * 4];
        b0B = wp0[(kk + 2) * 64];
        b1B = wp1[(kk + 2) * 64];
        c0 = __builtin_amdgcn_mfma_f32_16x16x32_bf16(a, b0, c0, 0, 0, 0);
        c1 = __builtin_amdgcn_mfma_f32_16x16x32_bf16(a, b1, c1, 0, 0, 0);
    }
    c0 = __builtin_amdgcn_mfma_f32_16x16x32_bf16(aA, b0A, c0, 0, 0, 0);
    c1 = __builtin_amdgcn_mfma_f32_16x16x32_bf16(aA, b1A, c1, 0, 0, 0);
    c0 = __builtin_amdgcn_mfma_f32_16x16x32_bf16(aB, b0B, c0, 0, 0, 0);
    c1 = __builtin_amdgcn_mfma_f32_16x16x32_bf16(aB, b1B, c1, 0, 0, 0);

#define EPIM(NT, CM) do {                                                        \
    int ch = (NT) * 16 + trow;                                                   \
    if (ch < LIN2) {                                                             \
        float bia = bm[ch];                                                      \
        _Pragma("unroll")                                                        \
        for (int reg = 0; reg < 4; ++reg) {                                      \
            float v = LEAKY(CM[reg] + bia);                                      \
            h[(size_t)(m0 + 4 * g + reg) * LIN2 + ch] = v;                       \
        }                                                                        \
    }                                                                            \
} while (0)

    EPIM(q,      c0);
    EPIM(q + 14, c1);
#undef EPIM
}

// ====== out[b] = h[b] . Wo + bo ================================================
__global__ __launch_bounds__(256) void final_reduce(
    const float* __restrict__ h, const float* __restrict__ Wo,
    const float* __restrict__ bo, float* __restrict__ out)
{
    const int tid = threadIdx.x;
    const int wid = tid >> 6, lane = tid & 63;
    const int b = blockIdx.x * 4 + wid;
    float s = 0.f;
    #pragma unroll
    for (int j = 0; j < 7; ++j) {
        int o = lane + 64 * j;
        if (o < LIN2) s += h[(size_t)b * LIN2 + o] * Wo[o];
    }
    for (int off = 32; off; off >>= 1) s += __shfl_down(s, off);
    if (lane == 0) out[b] = s + bo[0];
}

extern "C" void kernel_launch(void* const* d_in, const int* in_sizes, int n_in,
                              void* d_out, int out_size, void* d_ws, size_t ws_size,
                              hipStream_t stream) {
    const float* image = (const float*)d_in[0];
    const int*   sent  = (const int*)  d_in[1];
    const float* emb   = (const float*)d_in[2];
    const float* W1    = (const float*)d_in[3];
    const float* b1    = (const float*)d_in[4];
    const float* W2    = (const float*)d_in[5];
    const float* b2    = (const float*)d_in[6];
    const float* W3    = (const float*)d_in[7];
    const float* b3    = (const float*)d_in[8];
    const float* Wm    = (const float*)d_in[9];
    const float* bm    = (const float*)d_in[10];
    const float* Wo    = (const float*)d_in[11];
    const float* bo    = (const float*)d_in[12];
    float* out = (float*)d_out;

    // ws layout — all regions disjoint, single writer each, rewritten every call
    unsigned short* W1t = (unsigned short*)d_ws;
    unsigned short* W2t = W1t + (size_t)T1 * 512;
    unsigned short* W3t = W2t + (size_t)T2 * 512;
    unsigned short* Wmt = W3t + (size_t)T3 * 512;
    unsigned short* feats = Wmt + (size_t)TM * 512;      // B_*FK bf16
    float* h = (float*)(feats + (size_t)B_ * FK);        // B_*LIN2 f32

    convert_all<<<(TTOT * 64 + 255) / 256, 256, 0, stream>>>(
        W1, W2, W3, Wm, W1t, W2t, W3t, Wmt);

    conv_fused<<<B_ / 2, 512, 0, stream>>>(
        sent, emb, W1t, b1, W2t, b2, W3t, b3, image, feats);

    final_mfma<<<224, 256, 0, stream>>>(feats, Wmt, bm, h);
    final_reduce<<<B_ / 4, 256, 0, stream>>>(h, Wo, bo, out);
}

// Round 17
// 96.923 us; speedup vs baseline: 1.3297x; 1.0164x over previous
//
#include <hip/hip_runtime.h>
#include <hip/hip_bf16.h>

#define LEAKY(v) ((v) > 0.0f ? (v) : 0.01f * (v))

constexpr int B_   = 1024;
constexpr int PAD  = 30;
constexpr int E    = 512;
constexpr int IMG  = 2048;
constexpr int C1   = 200;
constexpr int C2   = 300;
constexpr int C3   = 300;
constexpr int LIN2 = 400;

constexpr int NT1P = 16, KT1 = 48;
constexpr int NT2P = 20, KT2 = 21;
constexpr int NT3P = 24, KT3 = 30;
constexpr int NTMP = 28, KTM = 83;
constexpr int FK  = 2656;

constexpr int T1 = NT1P * KT1;       // 768
constexpr int T2 = NT2P * KT2;       // 420
constexpr int T3 = NT3P * KT3;       // 720
constexpr int TM = NTMP * KTM;       // 2324
constexpr int TTOT = T1 + T2 + T3 + TM;

typedef __attribute__((ext_vector_type(8))) short bf16x8;
typedef __attribute__((ext_vector_type(4))) float f32x4;

__device__ inline unsigned short f2bf(float f) {
    __hip_bfloat16 h = __float2bfloat16(f);
    return *reinterpret_cast<unsigned short*>(&h);
}
__device__ inline float bf2f(unsigned short u) {
    unsigned int b = ((unsigned int)u) << 16;
    return __uint_as_float(b);
}

// ================= fused weight converter (unchanged, verified) =================
__global__ __launch_bounds__(256) void convert_all(
    const float* __restrict__ W1, const float* __restrict__ W2,
    const float* __restrict__ W3, const float* __restrict__ Wm,
    unsigned short* __restrict__ W1t, unsigned short* __restrict__ W2t,
    unsigned short* __restrict__ W3t, unsigned short* __restrict__ Wmt)
{
    int idx = blockIdx.x * 256 + threadIdx.x;
    if (idx >= TTOT * 64) return;
    int lane = idx & 63, t = idx >> 6;
    unsigned short v[8];

    if (t < T1) {
        int kk = t % KT1, nt = t / KT1;
        int ch = nt * 16 + (lane & 15);
        int k0 = kk * 32 + (lane >> 4) * 8;
        #pragma unroll
        for (int j = 0; j < 8; ++j)
            v[j] = (ch < C1) ? f2bf(W1[(size_t)ch * (3*E) + k0 + j]) : (unsigned short)0;
        ushort4* dst = reinterpret_cast<ushort4*>(W1t) + (size_t)t * 128 + lane * 2;
        dst[0] = ushort4{v[0],v[1],v[2],v[3]};
        dst[1] = ushort4{v[4],v[5],v[6],v[7]};
    } else if (t < T1 + T2) {
        int tt = t - T1;
        int kk = tt % KT2, nt = tt / KT2;
        int ch = nt * 16 + (lane & 15);
        int rowoff = kk / 7;
        int cbase  = (kk % 7) * 32 + (lane >> 4) * 8;
        #pragma unroll
        for (int j = 0; j < 8; ++j) {
            int c = cbase + j;
            v[j] = (ch < C2 && c < C1) ? f2bf(W2[(size_t)ch * (3*C1) + rowoff * C1 + c])
                                       : (unsigned short)0;
        }
        ushort4* dst = reinterpret_cast<ushort4*>(W2t) + (size_t)tt * 128 + lane * 2;
        dst[0] = ushort4{v[0],v[1],v[2],v[3]};
        dst[1] = ushort4{v[4],v[5],v[6],v[7]};
    } else if (t < T1 + T2 + T3) {
        int tt = t - T1 - T2;
        int kk = tt % KT3, nt = tt / KT3;
        int ch = nt * 16 + (lane & 15);
        int rowoff = kk / 10;
        int cbase  = (kk % 10) * 32 + (lane >> 4) * 8;
        #pragma unroll
        for (int j = 0; j < 8; ++j) {
            int c = cbase + j;
            v[j] = (ch < C3 && c < C2) ? f2bf(W3[(size_t)ch * (3*C2) + rowoff * C2 + c])
                                       : (unsigned short)0;
        }
        ushort4* dst = reinterpret_cast<ushort4*>(W3t) + (size_t)tt * 128 + lane * 2;
        dst[0] = ushort4{v[0],v[1],v[2],v[3]};
        dst[1] = ushort4{v[4],v[5],v[6],v[7]};
    } else {
        int tt = t - T1 - T2 - T3;
        int kk = tt % KTM, nt = tt / KTM;
        int ch = nt * 16 + (lane & 15);
        int kbase = kk * 32 + (lane >> 4) * 8;
        #pragma unroll
        for (int j = 0; j < 8; ++j) {
            int k = kbase + j;
            v[j] = (ch < LIN2 && k < 2648) ? f2bf(Wm[(size_t)ch * 2648 + k])
                                           : (unsigned short)0;
        }
        ushort4* dst = reinterpret_cast<ushort4*>(Wmt) + (size_t)tt * 128 + lane * 2;
        dst[0] = ushort4{v[0],v[1],v[2],v[3]};
        dst[1] = ushort4{v[4],v[5],v[6],v[7]};
    }
}

// ====== conv_fused v2b: image-copy first, pad-tile elision in conv2/conv3 ======
// 512 blocks x 512 thr. LDS ~34.3 KB.
__global__ __launch_bounds__(512, 4) void conv_fused(
    const int* __restrict__ sent, const float* __restrict__ emb,
    const unsigned short* __restrict__ W1t, const float* __restrict__ b1,
    const unsigned short* __restrict__ W2t, const float* __restrict__ b2,
    const unsigned short* __restrict__ W3t, const float* __restrict__ b3,
    const float* __restrict__ image, unsigned short* __restrict__ feats)
{
    const int blk = blockIdx.x;            // batches 2*blk, 2*blk+1
    const int tid = threadIdx.x;
    __shared__ unsigned short xs[66 * 256];   // 33,792 B
    __shared__ float rs[64];
    __shared__ float rs2[36];
    __shared__ float rs3[12];
    char* xsb = reinterpret_cast<char*>(xs);

    const int wid = tid >> 6, lane = tid & 63;
    const int kg = lane >> 4, trow = lane & 15, g = kg;

    // ---- Phase 0: image -> feats bf16 (independent of all LDS phases; issue
    // first so its HBM latency hides under the conv chain) ----
    for (int idx = tid; idx < 2 * 257; idx += 512) {
        int bl = idx / 257, c = idx % 257;
        int b = 2 * blk + bl;
        if (c < 256) {
            const float4* src = reinterpret_cast<const float4*>(
                image + (size_t)b * IMG + c * 8);
            float4 a = src[0], d = src[1];
            ushort4* dst = reinterpret_cast<ushort4*>(feats + (size_t)b * FK + 600 + c * 8);
            dst[0] = ushort4{f2bf(a.x),f2bf(a.y),f2bf(a.z),f2bf(a.w)};
            dst[1] = ushort4{f2bf(d.x),f2bf(d.y),f2bf(d.z),f2bf(d.w)};
        } else {
            ushort4* dst = reinterpret_cast<ushort4*>(feats + (size_t)b * FK + 2648);
            dst[0] = ushort4{0,0,0,0};
            dst[1] = ushort4{0,0,0,0};
        }
    }

    const bf16x8* wb1 = reinterpret_cast<const bf16x8*>(W1t);
    const bf16x8* wp0 = wb1 + (size_t)((wid    ) * KT1) * 64 + lane;
    const bf16x8* wp1 = wb1 + (size_t)((wid + 8) * KT1) * 64 + lane;

    f32x4 c00={0,0,0,0},c01={0,0,0,0},c02={0,0,0,0},c03={0,0,0,0};
    f32x4 c10={0,0,0,0},c11={0,0,0,0},c12={0,0,0,0},c13={0,0,0,0};

    // ---- Phase 1+2: two E-halves; stage 256 cols of all rows, then 24 K-steps --
    #pragma unroll
    for (int h = 0; h < 2; ++h) {
        if (h == 1) __syncthreads();   // protect half-0 reads before overwrite

        #pragma unroll
        for (int r8 = 0; r8 < 8; ++r8) {
            int r = wid + 8 * r8;
            if (r < 60) {
                int bl = r / 30, rr = r % 30;
                int R = bl * 32 + rr;
                int row = sent[(2 * blk + bl) * PAD + rr];
                float4 e = reinterpret_cast<const float4*>(
                    emb + (size_t)row * E + h * 256)[lane];
                float sum = e.x + e.y + e.z + e.w;
                ushort4 pk4{f2bf(e.x), f2bf(e.y), f2bf(e.z), f2bf(e.w)};
                int c = lane >> 1;
                int bo = R * 512 + ((c ^ (R & 7)) << 4) + (lane & 1) * 8;
                *reinterpret_cast<ushort4*>(xsb + bo) = pk4;
                for (int off = 32; off; off >>= 1) sum += __shfl_down(sum, off);
                if (lane == 0) { if (h == 0) rs[R] = sum; else rs[R] += sum; }
            }
        }
        if (tid < 384) {
            int zi = tid >> 6;
            int R = (zi < 2) ? (30 + zi) : (60 + zi);
            int c = lane >> 1;
            int bo = R * 512 + ((c ^ (R & 7)) << 4) + (lane & 1) * 8;
            *reinterpret_cast<ushort4*>(xsb + bo) = ushort4{0,0,0,0};
        }
        if (h == 0 && tid < 4) {
            const int pr[4] = {30, 31, 62, 63};
            rs[pr[tid]] = 0.f;
        }
        __syncthreads();

        // conv1 K-steps touching this half: kk = rowoff*16 + h*8 + cc, cc 0..7
        if (wid < 5) {
            #pragma unroll
            for (int rowoff = 0; rowoff < 3; ++rowoff) {
                const int R0 = trow + rowoff;
                const int R1 = R0 + 16, R2 = R0 + 32, R3 = R0 + 48;
                #pragma unroll
                for (int cc = 0; cc < 8; ++cc) {
                    const int kk = rowoff * 16 + h * 8 + cc;
                    const int ch2 = cc * 4 + kg;
                    bf16x8 a0 = *reinterpret_cast<const bf16x8*>(
                        xsb + R0 * 512 + (((ch2) ^ (R0 & 7)) << 4));
                    bf16x8 a1 = *reinterpret_cast<const bf16x8*>(
                        xsb + R1 * 512 + (((ch2) ^ (R1 & 7)) << 4));
                    bf16x8 a2 = *reinterpret_cast<const bf16x8*>(
                        xsb + R2 * 512 + (((ch2) ^ (R2 & 7)) << 4));
                    bf16x8 a3 = *reinterpret_cast<const bf16x8*>(
                        xsb + R3 * 512 + (((ch2) ^ (R3 & 7)) << 4));
                    bf16x8 b0 = wp0[kk * 64];
                    bf16x8 b1v = wp1[kk * 64];
                    c00 = __builtin_amdgcn_mfma_f32_16x16x32_bf16(a0, b0, c00, 0, 0, 0);
                    c01 = __builtin_amdgcn_mfma_f32_16x16x32_bf16(a1, b0, c01, 0, 0, 0);
                    c02 = __builtin_amdgcn_mfma_f32_16x16x32_bf16(a2, b0, c02, 0, 0, 0);
                    c03 = __builtin_amdgcn_mfma_f32_16x16x32_bf16(a3, b0, c03, 0, 0, 0);
                    c10 = __builtin_amdgcn_mfma_f32_16x16x32_bf16(a0, b1v, c10, 0, 0, 0);
                    c11 = __builtin_amdgcn_mfma_f32_16x16x32_bf16(a1, b1v, c11, 0, 0, 0);
                    c12 = __builtin_amdgcn_mfma_f32_16x16x32_bf16(a2, b1v, c12, 0, 0, 0);
                    c13 = __builtin_amdgcn_mfma_f32_16x16x32_bf16(a3, b1v, c13, 0, 0, 0);
                }
            }
        } else {
            #pragma unroll
            for (int rowoff = 0; rowoff < 3; ++rowoff) {
                const int R0 = trow + rowoff;
                const int R1 = R0 + 16, R2 = R0 + 32, R3 = R0 + 48;
                #pragma unroll
                for (int cc = 0; cc < 8; ++cc) {
                    const int kk = rowoff * 16 + h * 8 + cc;
                    const int ch2 = cc * 4 + kg;
                    bf16x8 a0 = *reinterpret_cast<const bf16x8*>(
                        xsb + R0 * 512 + (((ch2) ^ (R0 & 7)) << 4));
                    bf16x8 a1 = *reinterpret_cast<const bf16x8*>(
                        xsb + R1 * 512 + (((ch2) ^ (R1 & 7)) << 4));
                    bf16x8 a2 = *reinterpret_cast<const bf16x8*>(
                        xsb + R2 * 512 + (((ch2) ^ (R2 & 7)) << 4));
                    bf16x8 a3 = *reinterpret_cast<const bf16x8*>(
                        xsb + R3 * 512 + (((ch2) ^ (R3 & 7)) << 4));
                    bf16x8 b0 = wp0[kk * 64];
                    c00 = __builtin_amdgcn_mfma_f32_16x16x32_bf16(a0, b0, c00, 0, 0, 0);
                    c01 = __builtin_amdgcn_mfma_f32_16x16x32_bf16(a1, b0, c01, 0, 0, 0);
                    c02 = __builtin_amdgcn_mfma_f32_16x16x32_bf16(a2, b0, c02, 0, 0, 0);
                    c03 = __builtin_amdgcn_mfma_f32_16x16x32_bf16(a3, b0, c03, 0, 0, 0);
                }
            }
        }
    }
    __syncthreads();   // emb region dead

    // ---- Phase 3: zero y1 region (36 rows x 512B) ----
    for (int idx = tid; idx < 36 * 32; idx += 512) {
        int r = idx >> 5, ck = idx & 31;
        union { ushort4 u4[2]; bf16x8 v; } pk;
        pk.u4[0] = ushort4{0,0,0,0}; pk.u4[1] = ushort4{0,0,0,0};
        *reinterpret_cast<bf16x8*>(xsb + r * 512 + (ck << 4)) = pk.v;
    }
    __syncthreads();

    // ---- Phase 4: conv1 epilogue -> y1 LDS (bf16, conv2-swizzled) ----
#define EPIM1(MT, CM) do {                                                       \
    int bl = (MT) >> 1;                                                          \
    int mloc = ((MT) & 1) * 16;                                                  \
    _Pragma("unroll")                                                            \
    for (int hf = 0; hf < 2; ++hf) {                                             \
        int wl = mloc + 4 * g + 2 * hf;                                          \
        int tp = wl >> 1;                                                        \
        if (tp < 14) {                                                           \
            float v0 = CM[2*hf] + bia, v1 = CM[2*hf+1] + bia;                    \
            v0 = LEAKY(v0); v1 = LEAKY(v1);                                      \
            int rb = bl * 32 + wl;                                               \
            if (rs[rb] + rs[rb+1] + rs[rb+2] == 0.f) v0 = 0.f;                   \
            if (rs[rb+1] + rs[rb+2] + rs[rb+3] == 0.f) v1 = 0.f;                 \
            int rg = bl * 18 + tp;                                               \
            int bo = rg * 512 + ((((ch) >> 3) ^ (rg & 7)) << 4) + ((ch) & 7) * 2;\
            *reinterpret_cast<unsigned short*>(xsb + bo) = f2bf(fmaxf(v0, v1));  \
        }                                                                        \
    }                                                                            \
} while (0)

#define EPI1(NTI, CA, CB, CC, CD) do {                                           \
    int ch = (wid + 8 * (NTI)) * 16 + trow;                                      \
    if (ch < C1) {                                                               \
        float bia = b1[ch];                                                      \
        EPIM1(0, CA); EPIM1(1, CB); EPIM1(2, CC); EPIM1(3, CD);                  \
    }                                                                            \
} while (0)

    EPI1(0, c00, c01, c02, c03);
    if (wid < 5) {
        EPI1(1, c10, c11, c12, c13);
    }
#undef EPI1
#undef EPIM1
    __syncthreads();

    // ---- Phase 5: y1 rowsums (36 rows x 256) ----
    for (int r = wid; r < 36; r += 8) {
        float s = 0.f;
        #pragma unroll
        for (int j = 0; j < 4; ++j) {
            int e = lane + 64 * j;
            int chunk = e >> 3, within = e & 7;
            s += bf2f(*reinterpret_cast<unsigned short*>(
                xsb + r * 512 + ((chunk ^ (r & 7)) << 4) + within * 2));
        }
        for (int off = 32; off; off >>= 1) s += __shfl_down(s, off);
        if (lane == 0) rs2[r] = s;
    }
    __syncthreads();

    // ---- Phase 6: conv2 K-loop; waves 0-2 own 3 nt, waves 3-7 own 2 nt ----
    const bf16x8* wb2 = reinterpret_cast<const bf16x8*>(W2t);
    const int nt2a = wid, nt2b = wid + 8;
    const int nt2c = (wid < 3) ? (wid + 16) : 18;   // third tile real only wid<3
    const bf16x8* q0 = wb2 + (size_t)(nt2a * KT2) * 64 + lane;
    const bf16x8* q1 = wb2 + (size_t)(nt2b * KT2) * 64 + lane;
    const bf16x8* q2 = wb2 + (size_t)(nt2c * KT2) * 64 + lane;

    f32x4 d00={0,0,0,0},d01={0,0,0,0};
    f32x4 d10={0,0,0,0},d11={0,0,0,0};
    f32x4 d20={0,0,0,0},d21={0,0,0,0};

    if (wid < 3) {
        int kidx = 0;
        #pragma unroll
        for (int rowoff = 0; rowoff < 3; ++rowoff) {
            const int R0 = trow + rowoff;
            const int R1 = R0 + 18;
            const int b3_0 = R0 * 512 + (((R0 & 7) ^ kg) << 4);
            const int b3_1 = R1 * 512 + (((R1 & 7) ^ kg) << 4);
            #pragma unroll
            for (int cc = 0; cc < 7; ++cc, ++kidx) {
                bf16x8 a0 = *reinterpret_cast<const bf16x8*>(xsb + (b3_0 ^ (cc << 6)));
                bf16x8 a1 = *reinterpret_cast<const bf16x8*>(xsb + (b3_1 ^ (cc << 6)));
                bf16x8 b0 = q0[kidx * 64];
                bf16x8 b1v = q1[kidx * 64];
                bf16x8 b2v = q2[kidx * 64];
                d00 = __builtin_amdgcn_mfma_f32_16x16x32_bf16(a0, b0,  d00, 0, 0, 0);
                d01 = __builtin_amdgcn_mfma_f32_16x16x32_bf16(a1, b0,  d01, 0, 0, 0);
                d10 = __builtin_amdgcn_mfma_f32_16x16x32_bf16(a0, b1v, d10, 0, 0, 0);
                d11 = __builtin_amdgcn_mfma_f32_16x16x32_bf16(a1, b1v, d11, 0, 0, 0);
                d20 = __builtin_amdgcn_mfma_f32_16x16x32_bf16(a0, b2v, d20, 0, 0, 0);
                d21 = __builtin_amdgcn_mfma_f32_16x16x32_bf16(a1, b2v, d21, 0, 0, 0);
            }
        }
    } else {
        int kidx = 0;
        #pragma unroll
        for (int rowoff = 0; rowoff < 3; ++rowoff) {
            const int R0 = trow + rowoff;
            const int R1 = R0 + 18;
            const int b3_0 = R0 * 512 + (((R0 & 7) ^ kg) << 4);
            const int b3_1 = R1 * 512 + (((R1 & 7) ^ kg) << 4);
            #pragma unroll
            for (int cc = 0; cc < 7; ++cc, ++kidx) {
                bf16x8 a0 = *reinterpret_cast<const bf16x8*>(xsb + (b3_0 ^ (cc << 6)));
                bf16x8 a1 = *reinterpret_cast<const bf16x8*>(xsb + (b3_1 ^ (cc << 6)));
                bf16x8 b0 = q0[kidx * 64];
                bf16x8 b1v = q1[kidx * 64];
                d00 = __builtin_amdgcn_mfma_f32_16x16x32_bf16(a0, b0,  d00, 0, 0, 0);
                d01 = __builtin_amdgcn_mfma_f32_16x16x32_bf16(a1, b0,  d01, 0, 0, 0);
                d10 = __builtin_amdgcn_mfma_f32_16x16x32_bf16(a0, b1v, d10, 0, 0, 0);
                d11 = __builtin_amdgcn_mfma_f32_16x16x32_bf16(a1, b1v, d11, 0, 0, 0);
            }
        }
    }
    __syncthreads();   // y1 region dead

    // ---- Phase 7: zero y2 region (15 rows x 640B) ----
    for (int idx = tid; idx < 15 * 40; idx += 512) {
        int r = idx / 40, ck = idx % 40;
        union { ushort4 u4[2]; bf16x8 v; } pk;
        pk.u4[0] = ushort4{0,0,0,0}; pk.u4[1] = ushort4{0,0,0,0};
        *reinterpret_cast<bf16x8*>(xsb + r * 640 + (ck << 4)) = pk.v;
    }
    __syncthreads();

    // ---- Phase 8: conv2 epilogue -> y2 LDS (bf16, conv3-swizzled) ----
#define EPI2F(NT, DA, DB) do {                                                   \
    int ch = (NT) * 16 + trow;                                                   \
    if (ch < C2) {                                                               \
        float bia = b2[ch];                                                      \
        _Pragma("unroll")                                                        \
        for (int hf = 0; hf < 2; ++hf) {                                         \
            int t0 = 4 * g + 2 * hf;                                             \
            if (t0 < 12) {                                                       \
                { float v0 = LEAKY(DA[2*hf]   + bia);                            \
                  float v1 = LEAKY(DA[2*hf+1] + bia);                            \
                  if (rs2[t0] + rs2[t0+1] + rs2[t0+2] == 0.f) v0 = 0.f;          \
                  if (rs2[t0+1] + rs2[t0+2] + rs2[t0+3] == 0.f) v1 = 0.f;        \
                  int rg = (t0 >> 1);                                            \
                  int bo = rg * 640 + ((((ch)>>3) ^ (rg & 7)) << 4) + ((ch)&7)*2;\
                  *reinterpret_cast<unsigned short*>(xsb + bo) = f2bf(fmaxf(v0, v1)); } \
                { float v0 = LEAKY(DB[2*hf]   + bia);                            \
                  float v1 = LEAKY(DB[2*hf+1] + bia);                            \
                  int rb = 18 + t0;                                              \
                  if (rs2[rb] + rs2[rb+1] + rs2[rb+2] == 0.f) v0 = 0.f;          \
                  if (rs2[rb+1] + rs2[rb+2] + rs2[rb+3] == 0.f) v1 = 0.f;        \
                  int rg = 6 + (t0 >> 1);                                        \
                  int bo = rg * 640 + ((((ch)>>3) ^ (rg & 7)) << 4) + ((ch)&7)*2;\
                  *reinterpret_cast<unsigned short*>(xsb + bo) = f2bf(fmaxf(v0, v1)); } \
            }                                                                    \
        }                                                                        \
    }                                                                            \
} while (0)

    EPI2F(nt2a, d00, d01);
    EPI2F(nt2b, d10, d11);
    if (wid < 3) {
        EPI2F(nt2c, d20, d21);
    }
#undef EPI2F
    __syncthreads();

    // ---- Phase 9: y2 rowsums (12 rows x 320) ----
    for (int r = wid; r < 12; r += 8) {
        float s = 0.f;
        #pragma unroll
        for (int j = 0; j < 5; ++j) {
            int e = lane + 64 * j;
            int chunk = e >> 3, within = e & 7;
            s += bf2f(*reinterpret_cast<unsigned short*>(
                xsb + r * 640 + ((chunk ^ (r & 7)) << 4) + within * 2));
        }
        for (int off = 32; off; off >>= 1) s += __shfl_down(s, off);
        if (lane == 0) rs3[r] = s;
    }
    __syncthreads();

    // ---- Phase 10: conv3 K-loop; waves 0-2 own 3 nt, waves 3-7 own 2 nt ----
    const int rbase = (trow < 8) ? (6 * (trow >> 2) + (trow & 3)) : 12;

    const bf16x8* wb3 = reinterpret_cast<const bf16x8*>(W3t);
    const int nt3a = wid, nt3b = wid + 8;
    const int nt3c = (wid < 3) ? (wid + 16) : 18;
    const bf16x8* p0 = wb3 + (size_t)(nt3a * KT3) * 64 + lane;
    const bf16x8* p1 = wb3 + (size_t)(nt3b * KT3) * 64 + lane;
    const bf16x8* p2 = wb3 + (size_t)(nt3c * KT3) * 64 + lane;

    f32x4 e0={0,0,0,0},e1={0,0,0,0},e2={0,0,0,0};

    if (wid < 3) {
        int kidx = 0;
        #pragma unroll
        for (int rowoff = 0; rowoff < 3; ++rowoff) {
            const int R0 = rbase + rowoff;
            #pragma unroll
            for (int cc = 0; cc < 10; ++cc, ++kidx) {
                int chunk = cc * 4 + kg;
                bf16x8 a0 = *reinterpret_cast<const bf16x8*>(
                    xsb + R0 * 640 + ((chunk ^ (R0 & 7)) << 4));
                bf16x8 b0 = p0[kidx * 64];
                bf16x8 b1v = p1[kidx * 64];
                bf16x8 b2v = p2[kidx * 64];
                e0 = __builtin_amdgcn_mfma_f32_16x16x32_bf16(a0, b0,  e0, 0, 0, 0);
                e1 = __builtin_amdgcn_mfma_f32_16x16x32_bf16(a0, b1v, e1, 0, 0, 0);
                e2 = __builtin_amdgcn_mfma_f32_16x16x32_bf16(a0, b2v, e2, 0, 0, 0);
            }
        }
    } else {
        int kidx = 0;
        #pragma unroll
        for (int rowoff = 0; rowoff < 3; ++rowoff) {
            const int R0 = rbase + rowoff;
            #pragma unroll
            for (int cc = 0; cc < 10; ++cc, ++kidx) {
                int chunk = cc * 4 + kg;
                bf16x8 a0 = *reinterpret_cast<const bf16x8*>(
                    xsb + R0 * 640 + ((chunk ^ (R0 & 7)) << 4));
                bf16x8 b0 = p0[kidx * 64];
                bf16x8 b1v = p1[kidx * 64];
                e0 = __builtin_amdgcn_mfma_f32_16x16x32_bf16(a0, b0,  e0, 0, 0, 0);
                e1 = __builtin_amdgcn_mfma_f32_16x16x32_bf16(a0, b1v, e1, 0, 0, 0);
            }
        }
    }

    // ---- Phase 11: conv3 epilogue -> feats (global). reg = window, g = batch ---
#define EPI3F(NT, EM) do {                                                       \
    int ch = (NT) * 16 + trow;                                                   \
    if (ch < C3 && g < 2) {                                                      \
        float bia = b3[ch];                                                      \
        _Pragma("unroll")                                                        \
        for (int tp = 0; tp < 2; ++tp) {                                         \
            int rb = g * 6 + 2 * tp;                                             \
            float v0 = LEAKY(EM[2*tp]   + bia);                                  \
            float v1 = LEAKY(EM[2*tp+1] + bia);                                  \
            if (rs3[rb] + rs3[rb+1] + rs3[rb+2] == 0.f) v0 = 0.f;                \
            if (rs3[rb+1] + rs3[rb+2] + rs3[rb+3] == 0.f) v1 = 0.f;              \
            feats[(size_t)(2 * blk + g) * FK + tp * C3 + ch] = f2bf(fmaxf(v0, v1)); \
        }                                                                        \
    }                                                                            \
} while (0)

    EPI3F(nt3a, e0);
    EPI3F(nt3b, e1);
    if (wid < 3) {
        EPI3F(nt3c, e2);
    }
#undef EPI3F
}

// ====== final GEMM: 224 blocks x 4 waves; wave = (mt, 2 nt), depth-2 prefetch ==
__global__ __launch_bounds__(256) void final_mfma(
    const unsigned short* __restrict__ feats, const unsigned short* __restrict__ Wmt,
    const float* __restrict__ bm, float* __restrict__ h)
{
    const int tid = threadIdx.x;
    const int wid = tid >> 6, lane = tid & 63;
    const int gw = blockIdx.x * 4 + wid;          // 0..895
    const int mt = gw / 14, q = gw % 14;
    const int kg = lane >> 4, trow = lane & 15, g = kg;
    const int m0 = mt * 16;

    const bf16x8* ap = reinterpret_cast<const bf16x8*>(feats)
                       + (size_t)(m0 + trow) * (FK / 8) + kg;
    const bf16x8* wb = reinterpret_cast<const bf16x8*>(Wmt);
    const bf16x8* wp0 = wb + (size_t)((q     ) * KTM) * 64 + lane;
    const bf16x8* wp1 = wb + (size_t)((q + 14) * KTM) * 64 + lane;

    f32x4 c0 = {0,0,0,0}, c1 = {0,0,0,0};

    bf16x8 aA = ap[0],     aB = ap[4];
    bf16x8 b0A = wp0[0],   b1A = wp1[0];
    bf16x8 b0B = wp0[64],  b1B = wp1[64];
    for (int kk = 0; kk < KTM - 2; ++kk) {
        bf16x8 a = aA, b0 = b0A, b1 = b1A;
        aA = aB; b0A = b0B; b1A = b1B;
        aB  = ap [(kk + 2) * 4];
        b0B = wp0[(kk + 2) * 64];
        b1B = wp1[(kk + 2) * 64];
        c0 = __builtin_amdgcn_mfma_f32_16x16x32_bf16(a, b0, c0, 0, 0, 0);
        c1 = __builtin_amdgcn_mfma_f32_16x16x32_bf16(a, b1, c1, 0, 0, 0);
    }
    c0 = __builtin_amdgcn_mfma_f32_16x16x32_bf16(aA, b0A, c0, 0, 0, 0);
    c1 = __builtin_amdgcn_mfma_f32_16x16x32_bf16(aA, b1A, c1, 0, 0, 0);
    c0 = __builtin_amdgcn_mfma_f32_16x16x32_bf16(aB, b0B, c0, 0, 0, 0);
    c1 = __builtin_amdgcn_mfma_f32_16x16x32_bf16(aB, b1B, c1, 0, 0, 0);

#define EPIM(NT, CM) do {                                                        \
    int ch = (NT) * 16 + trow;                                                   \
    if (ch < LIN2) {                                                             \
        float bia = bm[ch];                                                      \
        _Pragma("unroll")                                                        \
        for (int reg = 0; reg < 4; ++reg) {                                      \
            float v = LEAKY(CM[reg] + bia);                                      \
            h[(size_t)(m0 + 4 * g + reg) * LIN2 + ch] = v;                       \
        }                                                                        \
    }                                                                            \
} while (0)

    EPIM(q,      c0);
    EPIM(q + 14, c1);
#undef EPIM
}

// ====== out[b] = h[b] . Wo + bo ================================================
__global__ __launch_bounds__(256) void final_reduce(
    const float* __restrict__ h, const float* __restrict__ Wo,
    const float* __restrict__ bo, float* __restrict__ out)
{
    const int tid = threadIdx.x;
    const int wid = tid >> 6, lane = tid & 63;
    const int b = blockIdx.x * 4 + wid;
    float s = 0.f;
    #pragma unroll
    for (int j = 0; j < 7; ++j) {
        int o = lane + 64 * j;
        if (o < LIN2) s += h[(size_t)b * LIN2 + o] * Wo[o];
    }
    for (int off = 32; off; off >>= 1) s += __shfl_down(s, off);
    if (lane == 0) out[b] = s + bo[0];
}

extern "C" void kernel_launch(void* const* d_in, const int* in_sizes, int n_in,
                              void* d_out, int out_size, void* d_ws, size_t ws_size,
                              hipStream_t stream) {
    const float* image = (const float*)d_in[0];
    const int*   sent  = (const int*)  d_in[1];
    const float* emb   = (const float*)d_in[2];
    const float* W1    = (const float*)d_in[3];
    const float* b1    = (const float*)d_in[4];
    const float* W2    = (const float*)d_in[5];
    const float* b2    = (const float*)d_in[6];
    const float* W3    = (const float*)d_in[7];
    const float* b3    = (const float*)d_in[8];
    const float* Wm    = (const float*)d_in[9];
    const float* bm    = (const float*)d_in[10];
    const float* Wo    = (const float*)d_in[11];
    const float* bo    = (const float*)d_in[12];
    float* out = (float*)d_out;

    // ws layout — all regions disjoint, single writer each, rewritten every call
    unsigned short* W1t = (unsigned short*)d_ws;
    unsigned short* W2t = W1t + (size_t)T1 * 512;
    unsigned short* W3t = W2t + (size_t)T2 * 512;
    unsigned short* Wmt = W3t + (size_t)T3 * 512;
    unsigned short* feats = Wmt + (size_t)TM * 512;      // B_*FK bf16
    float* h = (float*)(feats + (size_t)B_ * FK);        // B_*LIN2 f32

    convert_all<<<(TTOT * 64 + 255) / 256, 256, 0, stream>>>(
        W1, W2, W3, Wm, W1t, W2t, W3t, Wmt);

    conv_fused<<<B_ / 2, 512, 0, stream>>>(
        sent, emb, W1t, b1, W2t, b2, W3t, b3, image, feats);

    final_mfma<<<224, 256, 0, stream>>>(feats, Wmt, bm, h);
    final_reduce<<<B_ / 4, 256, 0, stream>>>(h, Wo, bo, out);
}